// Round 3
// baseline (2635.095 us; speedup 1.0000x reference)
//
#include <hip/hip_runtime.h>

#define DEG_CAP 64

__device__ __forceinline__ int rfl(int v) { return __builtin_amdgcn_readfirstlane(v); }

// ---------- edge MLP layer 1: he[E,16] = relu(ea @ w_e1 + b_e1) ----------
__global__ void k_he(const float* __restrict__ ea, const float* __restrict__ w,
                     const float* __restrict__ b, float* __restrict__ he, int E) {
  int e = blockIdx.x * blockDim.x + threadIdx.x;
  if (e >= E) return;
  const float4* eap = reinterpret_cast<const float4*>(ea + (size_t)e * 8);
  float4 a0 = eap[0], a1 = eap[1];
  float av[8] = {a0.x, a0.y, a0.z, a0.w, a1.x, a1.y, a1.z, a1.w};
  float o[16];
#pragma unroll
  for (int k = 0; k < 16; ++k) o[k] = b[k];
#pragma unroll
  for (int t = 0; t < 8; ++t) {
    float at = av[t];
#pragma unroll
    for (int k = 0; k < 16; ++k) o[k] = fmaf(at, w[t * 16 + k], o[k]);
  }
#pragma unroll
  for (int k = 0; k < 16; ++k) o[k] = fmaxf(o[k], 0.f);
  float4* hp = reinterpret_cast<float4*>(he + (size_t)e * 16);
  hp[0] = make_float4(o[0], o[1], o[2], o[3]);
  hp[1] = make_float4(o[4], o[5], o[6], o[7]);
  hp[2] = make_float4(o[8], o[9], o[10], o[11]);
  hp[3] = make_float4(o[12], o[13], o[14], o[15]);
}

// ---------- build capped CSR-by-dst ----------
__global__ void k_fill(const int* __restrict__ ei, int* __restrict__ cursor,
                       int* __restrict__ slots, int E) {
  int e = blockIdx.x * blockDim.x + threadIdx.x;
  if (e >= E) return;
  int dst = ei[E + e];
  int slot = atomicAdd(&cursor[dst], 1);
  if (slot < DEG_CAP) slots[(size_t)dst * DEG_CAP + slot] = e;
}

// ---------- main gather: msg aggregation + root + bias, BN stats ----------
// wave = node; lane = output channel h. Node-stream scalarized via
// readfirstlane so cursor/slots/ei/he/x come in on the scalar pipe (s_load)
// and the inner MLP is pure v_fma with one SGPR operand.
__global__ __launch_bounds__(256, 3) void k_gather(
    const float* __restrict__ x, const int* __restrict__ ei,
    const float* __restrict__ he, const int* __restrict__ cursor,
    const int* __restrict__ slots, const float* __restrict__ w_e2,
    const float* __restrict__ b_e2, const float* __restrict__ root,
    const float* __restrict__ conv_bias, float* __restrict__ hout,
    float* __restrict__ stats, int N, int E) {
  int lane = threadIdx.x & 63;
  int wid = rfl(blockIdx.x * (blockDim.x >> 6) + (threadIdx.x >> 6));
  int nw = gridDim.x * (blockDim.x >> 6);

  // per-lane (h = lane) constant weights in registers (128 VGPR)
  float w2r[16][8];
#pragma unroll
  for (int k = 0; k < 16; ++k)
#pragma unroll
    for (int f = 0; f < 8; ++f) w2r[k][f] = w_e2[k * 512 + f * 64 + lane];
  float b2r[8], rootr[8];
#pragma unroll
  for (int f = 0; f < 8; ++f) b2r[f] = b_e2[f * 64 + lane];
#pragma unroll
  for (int f = 0; f < 8; ++f) rootr[f] = root[f * 64 + lane];
  float cb = conv_bias[lane];

  float bnsum = 0.f, bnsq = 0.f;

  for (int n = wid; n < N; n += nw) {   // n is SGPR-uniform
    int d = cursor[n];                  // s_load
    int dc = min(d, DEG_CAP);
    const int* srow = slots + (size_t)n * DEG_CAP;
    float acc = 0.f;
    int i = 0;
    for (; i + 1 < dc; i += 2) {        // unroll-2: independent scalar loads
      int e0 = srow[i], e1 = srow[i + 1];
      int s0 = ei[e0], s1 = ei[e1];
      const float* h0 = he + (size_t)e0 * 16;
      const float* h1 = he + (size_t)e1 * 16;
      const float* x0 = x + (size_t)s0 * 8;
      const float* x1 = x + (size_t)s1 * 8;
      float p0[8], p1[8];
#pragma unroll
      for (int f = 0; f < 8; ++f) { p0[f] = b2r[f]; p1[f] = b2r[f]; }
#pragma unroll
      for (int k = 0; k < 16; ++k) {
        float a0 = h0[k], a1 = h1[k];   // s_load_dwordx8-able
#pragma unroll
        for (int f = 0; f < 8; ++f) {
          p0[f] = fmaf(a0, w2r[k][f], p0[f]);
          p1[f] = fmaf(a1, w2r[k][f], p1[f]);
        }
      }
      float m0 = 0.f, m1 = 0.f;
#pragma unroll
      for (int f = 0; f < 8; ++f) {
        m0 = fmaf(p0[f], x0[f], m0);
        m1 = fmaf(p1[f], x1[f], m1);
      }
      acc += m0 + m1;
    }
    if (i < dc) {
      int e0 = srow[i];
      int s0 = ei[e0];
      const float* h0 = he + (size_t)e0 * 16;
      const float* x0 = x + (size_t)s0 * 8;
      float p0[8];
#pragma unroll
      for (int f = 0; f < 8; ++f) p0[f] = b2r[f];
#pragma unroll
      for (int k = 0; k < 16; ++k) {
        float a0 = h0[k];
#pragma unroll
        for (int f = 0; f < 8; ++f) p0[f] = fmaf(a0, w2r[k][f], p0[f]);
      }
      float m0 = 0.f;
#pragma unroll
      for (int f = 0; f < 8; ++f) m0 = fmaf(p0[f], x0[f], m0);
      acc += m0;
    }
    float hval = cb + acc / (float)max(d, 1);
    const float* xn = x + (size_t)n * 8;  // uniform -> s_load
#pragma unroll
    for (int f = 0; f < 8; ++f) hval = fmaf(xn[f], rootr[f], hval);
    hout[(size_t)n * 64 + lane] = hval;
    bnsum += hval;
    bnsq += hval * hval;
  }
  atomicAdd(&stats[lane], bnsum);
  atomicAdd(&stats[64 + lane], bnsq);
}

// ---------- BN+ReLU + per-graph pooling (batch_index sorted -> chunked) ----------
__global__ void k_bnpool(const float* __restrict__ hbuf, const float* __restrict__ stats,
                         const int* __restrict__ batch, const float* __restrict__ gamma,
                         const float* __restrict__ beta, float* __restrict__ gsum,
                         unsigned int* __restrict__ gmax, int* __restrict__ gcnt, int N) {
  int lane = threadIdx.x & 63;
  int wid = blockIdx.x * (blockDim.x >> 6) + (threadIdx.x >> 6);
  int nw = gridDim.x * (blockDim.x >> 6);
  float m = stats[lane] / (float)N;
  float var = stats[64 + lane] / (float)N - m * m;
  float rs = rsqrtf(var + 1e-5f);
  float ga = gamma[lane], be = beta[lane];
  int per = (N + nw - 1) / nw;
  int n0 = wid * per;
  int n1 = min(N, n0 + per);
  int cur = -1, cnt = 0;
  float s = 0.f, mx = 0.f;
  for (int n = n0; n < n1; ++n) {
    int g = batch[n];  // wave-uniform, sorted
    float v = hbuf[(size_t)n * 64 + lane];
    float y = fmaxf(fmaf((v - m) * rs, ga, be), 0.f);
    if (g != cur) {
      if (cur >= 0) {
        atomicAdd(&gsum[cur * 64 + lane], s);
        atomicMax(&gmax[cur * 64 + lane], __float_as_uint(mx));
        if (lane == 0) atomicAdd(&gcnt[cur], cnt);
      }
      cur = g; s = 0.f; mx = 0.f; cnt = 0;
    }
    s += y; mx = fmaxf(mx, y); ++cnt;
  }
  if (cur >= 0) {
    atomicAdd(&gsum[cur * 64 + lane], s);
    atomicMax(&gmax[cur * 64 + lane], __float_as_uint(mx));
    if (lane == 0) atomicAdd(&gcnt[cur], cnt);
  }
}

// ---------- head layer 1 with fused pooling assembly ----------
// in-value(row,k) = k<64 ? gsum[row][k]/cnt : gmax[row][k-64]
__global__ void k_head_pool(const float* __restrict__ gsum,
                            const unsigned int* __restrict__ gmax,
                            const int* __restrict__ gcnt,
                            const float* __restrict__ W, const float* __restrict__ b,
                            const float* __restrict__ gamma, const float* __restrict__ beta,
                            float* __restrict__ out, int Kout) {
  int lane = threadIdx.x & 63;  // row (graph)
  int col = blockIdx.x * (blockDim.x >> 6) + (threadIdx.x >> 6);
  if (col >= Kout) return;
  float inv = 1.f / fmaxf((float)gcnt[lane], 1.f);
  float a = b[col];
#pragma unroll 4
  for (int k = 0; k < 64; ++k)
    a = fmaf(gsum[lane * 64 + k] * inv, W[(size_t)k * Kout + col], a);
#pragma unroll 4
  for (int k = 0; k < 64; ++k)
    a = fmaf(__uint_as_float(gmax[lane * 64 + k]), W[(size_t)(64 + k) * Kout + col], a);
  float sv = a, ss = a * a;
#pragma unroll
  for (int off = 32; off > 0; off >>= 1) {
    sv += __shfl_xor(sv, off);
    ss += __shfl_xor(ss, off);
  }
  float m = sv * (1.f / 64.f);
  float var = ss * (1.f / 64.f) - m * m;
  float y = fmaxf(fmaf((a - m) * rsqrtf(var + 1e-5f), gamma[col], beta[col]), 0.f);
  out[(size_t)lane * Kout + col] = y;
}

// ---------- head layer: out = relu(bn(in @ W + b)); wave = one column ----------
__global__ void k_head(const float* __restrict__ in, const float* __restrict__ W,
                       const float* __restrict__ b, const float* __restrict__ gamma,
                       const float* __restrict__ beta, float* __restrict__ out,
                       int Kin, int Kout) {
  int lane = threadIdx.x & 63;  // row (graph)
  int col = blockIdx.x * (blockDim.x >> 6) + (threadIdx.x >> 6);
  if (col >= Kout) return;
  const float4* ir = reinterpret_cast<const float4*>(in + (size_t)lane * Kin);
  float a = b[col];
  for (int k4 = 0; k4 < (Kin >> 2); ++k4) {
    float4 v = ir[k4];
    int k = k4 << 2;
    a = fmaf(v.x, W[(size_t)k * Kout + col], a);
    a = fmaf(v.y, W[(size_t)(k + 1) * Kout + col], a);
    a = fmaf(v.z, W[(size_t)(k + 2) * Kout + col], a);
    a = fmaf(v.w, W[(size_t)(k + 3) * Kout + col], a);
  }
  float sv = a, ss = a * a;
#pragma unroll
  for (int off = 32; off > 0; off >>= 1) {
    sv += __shfl_xor(sv, off);
    ss += __shfl_xor(ss, off);
  }
  float m = sv * (1.f / 64.f);
  float var = ss * (1.f / 64.f) - m * m;
  float y = fmaxf(fmaf((a - m) * rsqrtf(var + 1e-5f), gamma[col], beta[col]), 0.f);
  out[(size_t)lane * Kout + col] = y;
}

// ---------- final linear: [64,64] @ [64,10] + bout ----------
__global__ void k_out(const float* __restrict__ in, const float* __restrict__ W,
                      const float* __restrict__ b, float* __restrict__ out) {
  int t = threadIdx.x;
  if (t >= 640) return;
  int r = t / 10, c = t % 10;
  float a = b[c];
#pragma unroll
  for (int k = 0; k < 64; ++k) a = fmaf(in[r * 64 + k], W[k * 10 + c], a);
  out[t] = a;
}

extern "C" void kernel_launch(void* const* d_in, const int* in_sizes, int n_in,
                              void* d_out, int out_size, void* d_ws, size_t ws_size,
                              hipStream_t stream) {
  const float* x = (const float*)d_in[0];
  const int* ei = (const int*)d_in[1];
  const float* ea = (const float*)d_in[2];
  const int* batch = (const int*)d_in[3];
  const float* w_e1 = (const float*)d_in[4];
  const float* b_e1 = (const float*)d_in[5];
  const float* w_e2 = (const float*)d_in[6];
  const float* b_e2 = (const float*)d_in[7];
  const float* root = (const float*)d_in[8];
  const float* conv_bias = (const float*)d_in[9];
  const float* g_bnc = (const float*)d_in[10];
  const float* b_bnc = (const float*)d_in[11];
  const float* w1 = (const float*)d_in[12];
  const float* b1 = (const float*)d_in[13];
  const float* g1 = (const float*)d_in[14];
  const float* be1 = (const float*)d_in[15];
  const float* w2 = (const float*)d_in[16];
  const float* b2 = (const float*)d_in[17];
  const float* g2 = (const float*)d_in[18];
  const float* be2 = (const float*)d_in[19];
  const float* w3 = (const float*)d_in[20];
  const float* b3 = (const float*)d_in[21];
  const float* g3 = (const float*)d_in[22];
  const float* be3 = (const float*)d_in[23];
  const float* wout = (const float*)d_in[24];
  const float* bout = (const float*)d_in[25];

  int N = in_sizes[0] / 8;
  int E = in_sizes[1] / 2;

  char* wsb = (char*)d_ws;
  size_t off = 0;
  auto alloc = [&](size_t bytes) -> void* {
    void* p = wsb + off;
    off += (bytes + 255) & ~(size_t)255;
    return p;
  };
  float* he = (float*)alloc((size_t)E * 16 * 4);          // 32 MB
  int* cursor = (int*)alloc((size_t)N * 4);               // 0.2 MB
  int* slots = (int*)alloc((size_t)N * DEG_CAP * 4);      // 12.8 MB
  float* hbuf = (float*)alloc((size_t)N * 64 * 4);        // 12.8 MB
  float* zblk = (float*)alloc(8384 * 4);                  // stats+gsum+gmax+gcnt
  float* stats = zblk;                                    // 128
  float* gsum = zblk + 128;                               // 4096
  unsigned int* gmax = (unsigned int*)(zblk + 128 + 4096);// 4096
  int* gcnt = (int*)(zblk + 128 + 8192);                  // 64
  float* l1 = (float*)alloc(64 * 256 * 4);
  float* l2 = (float*)alloc(64 * 128 * 4);
  float* l3 = (float*)alloc(64 * 64 * 4);

  hipMemsetAsync(cursor, 0, (size_t)N * 4, stream);
  hipMemsetAsync(zblk, 0, 8384 * 4, stream);

  const int tb = 256;
  k_he<<<(E + tb - 1) / tb, tb, 0, stream>>>(ea, w_e1, b_e1, he, E);
  k_fill<<<(E + tb - 1) / tb, tb, 0, stream>>>(ei, cursor, slots, E);
  k_gather<<<4096, 256, 0, stream>>>(x, ei, he, cursor, slots, w_e2, b_e2, root,
                                     conv_bias, hbuf, stats, N, E);
  k_bnpool<<<512, 256, 0, stream>>>(hbuf, stats, batch, g_bnc, b_bnc, gsum, gmax, gcnt, N);
  k_head_pool<<<64, 256, 0, stream>>>(gsum, gmax, gcnt, w1, b1, g1, be1, l1, 256);
  k_head<<<32, 256, 0, stream>>>(l1, w2, b2, g2, be2, l2, 256, 128);
  k_head<<<16, 256, 0, stream>>>(l2, w3, b3, g3, be3, l3, 128, 64);
  k_out<<<1, 640, 0, stream>>>(l3, wout, bout, (float*)d_out);
}

// Round 6
// 368.405 us; speedup vs baseline: 7.1527x; 7.1527x over previous
//
#include <hip/hip_runtime.h>

#define DEG_CAP 64
#define ZROW 136  // 128 z values + 8 xsum

__device__ __forceinline__ int rfl(int v) { return __builtin_amdgcn_readfirstlane(v); }

// ---------- edge MLP layer 1: he[E,16] = relu(ea @ w_e1 + b_e1) ----------
__global__ void k_he(const float* __restrict__ ea, const float* __restrict__ w,
                     const float* __restrict__ b, float* __restrict__ he, int E) {
  int e = blockIdx.x * blockDim.x + threadIdx.x;
  if (e >= E) return;
  const float4* eap = reinterpret_cast<const float4*>(ea + (size_t)e * 8);
  float4 a0 = eap[0], a1 = eap[1];
  float av[8] = {a0.x, a0.y, a0.z, a0.w, a1.x, a1.y, a1.z, a1.w};
  float o[16];
#pragma unroll
  for (int k = 0; k < 16; ++k) o[k] = b[k];
#pragma unroll
  for (int t = 0; t < 8; ++t) {
    float at = av[t];
#pragma unroll
    for (int k = 0; k < 16; ++k) o[k] = fmaf(at, w[t * 16 + k], o[k]);
  }
#pragma unroll
  for (int k = 0; k < 16; ++k) o[k] = fmaxf(o[k], 0.f);
  float4* hp = reinterpret_cast<float4*>(he + (size_t)e * 16);
  hp[0] = make_float4(o[0], o[1], o[2], o[3]);
  hp[1] = make_float4(o[4], o[5], o[6], o[7]);
  hp[2] = make_float4(o[8], o[9], o[10], o[11]);
  hp[3] = make_float4(o[12], o[13], o[14], o[15]);
}

// ---------- build capped CSR-by-dst ----------
__global__ void k_fill(const int* __restrict__ ei, int* __restrict__ cursor,
                       int* __restrict__ slots, int E) {
  int e = blockIdx.x * blockDim.x + threadIdx.x;
  if (e >= E) return;
  int dst = ei[E + e];
  int slot = atomicAdd(&cursor[dst], 1);
  if (slot < DEG_CAP) slots[(size_t)dst * DEG_CAP + slot] = e;
}

// ---------- phase A: z[n][k][f] = sum_e he[e][k]*x[src][f]; xsum[n][f] ----------
// wave = node; lane l owns (k = l>>2, f = {2*(l&3), 2*(l&3)+1}): 2 FMA/edge.
__global__ void k_zgather(const float* __restrict__ x, const int* __restrict__ ei,
                          const float* __restrict__ he, const int* __restrict__ cursor,
                          const int* __restrict__ slots, float* __restrict__ zbuf,
                          int N) {
  int lane = threadIdx.x & 63;
  int n = rfl(blockIdx.x * (blockDim.x >> 6) + (threadIdx.x >> 6));
  if (n >= N) return;
  int k = lane >> 2;
  int f2 = (lane & 3) << 1;
  int d = cursor[n];                     // s_load (n uniform)
  int dc = min(d, DEG_CAP);
  int eid = (lane < dc) ? slots[(size_t)n * DEG_CAP + lane] : 0;
  int sid = ei[eid];  // per-lane gather, pre-loop (off critical path)
  float z0 = 0.f, z1 = 0.f, xs0 = 0.f, xs1 = 0.f;
  if (dc > 0) {
    int e0 = __shfl(eid, 0), s0 = __shfl(sid, 0);
    float hk = he[(size_t)e0 * 16 + k];
    float2 xv = *reinterpret_cast<const float2*>(x + (size_t)s0 * 8 + f2);
    for (int i = 1; i < dc; ++i) {   // 2-deep pipeline: next loads over current FMAs
      int e1 = __shfl(eid, i), s1 = __shfl(sid, i);
      float hk_n = he[(size_t)e1 * 16 + k];
      float2 xv_n = *reinterpret_cast<const float2*>(x + (size_t)s1 * 8 + f2);
      z0 = fmaf(hk, xv.x, z0);
      z1 = fmaf(hk, xv.y, z1);
      xs0 += xv.x; xs1 += xv.y;
      hk = hk_n; xv = xv_n;
    }
    z0 = fmaf(hk, xv.x, z0);
    z1 = fmaf(hk, xv.y, z1);
    xs0 += xv.x; xs1 += xv.y;
  }
  float2* zp = reinterpret_cast<float2*>(zbuf + (size_t)n * ZROW);
  zp[lane] = make_float2(z0, z1);
  if (lane < 4) zp[64 + lane] = make_float2(xs0, xs1);
}

// ---------- phase B: agg = z . w2 (+ xsum . b2), + root + bias, BN stats ----------
// wave = node (grid-stride); lane = h. w2r[128] loaded ONCE per wave, amortized
// over ~N/nw nodes. launch_bounds(256,2) -> 256-VGPR cap, ~160 live: no spill.
__global__ __launch_bounds__(256, 2) void k_wmix(
    const float* __restrict__ x, const int* __restrict__ cursor,
    const float* __restrict__ zbuf, const float* __restrict__ w_e2,
    const float* __restrict__ b_e2, const float* __restrict__ root,
    const float* __restrict__ conv_bias, float* __restrict__ hout,
    float* __restrict__ stats, int N) {
  int lane = threadIdx.x & 63;
  int wid = rfl(blockIdx.x * (blockDim.x >> 6) + (threadIdx.x >> 6));
  int nw = gridDim.x * (blockDim.x >> 6);

  float w2r[128];
#pragma unroll
  for (int j = 0; j < 128; ++j) {
    int k = j >> 3;
    int f = (((j >> 1) & 3) << 1) + (j & 1);
    w2r[j] = w_e2[k * 512 + f * 64 + lane];
  }
  float b2r[8], rootr[8];
#pragma unroll
  for (int f = 0; f < 8; ++f) b2r[f] = b_e2[f * 64 + lane];
#pragma unroll
  for (int f = 0; f < 8; ++f) rootr[f] = root[f * 64 + lane];
  float cb = conv_bias[lane];

  float bnsum = 0.f, bnsq = 0.f;
  for (int n = wid; n < N; n += nw) {    // n uniform -> zr/cursor/xn are s_loads
    const float* zr = zbuf + (size_t)n * ZROW;
    float agg = 0.f;
#pragma unroll
    for (int j = 0; j < 128; ++j) agg = fmaf(zr[j], w2r[j], agg);
    float xb = 0.f;
#pragma unroll
    for (int f = 0; f < 8; ++f) xb = fmaf(zr[128 + f], b2r[f], xb);
    int d = cursor[n];
    float hval = cb + (agg + xb) / (float)max(d, 1);
    const float* xn = x + (size_t)n * 8;
#pragma unroll
    for (int f = 0; f < 8; ++f) hval = fmaf(xn[f], rootr[f], hval);
    hout[(size_t)n * 64 + lane] = hval;
    bnsum += hval;
    bnsq += hval * hval;
  }
  atomicAdd(&stats[lane], bnsum);
  atomicAdd(&stats[64 + lane], bnsq);
}

// ---------- BN+ReLU + per-graph pooling (batch_index sorted -> chunked) ----------
__global__ void k_bnpool(const float* __restrict__ hbuf, const float* __restrict__ stats,
                         const int* __restrict__ batch, const float* __restrict__ gamma,
                         const float* __restrict__ beta, float* __restrict__ gsum,
                         unsigned int* __restrict__ gmax, int* __restrict__ gcnt, int N) {
  int lane = threadIdx.x & 63;
  int wid = blockIdx.x * (blockDim.x >> 6) + (threadIdx.x >> 6);
  int nw = gridDim.x * (blockDim.x >> 6);
  float m = stats[lane] / (float)N;
  float var = stats[64 + lane] / (float)N - m * m;
  float rs = rsqrtf(var + 1e-5f);
  float ga = gamma[lane], be = beta[lane];
  int per = (N + nw - 1) / nw;
  int n0 = wid * per;
  int n1 = min(N, n0 + per);
  int cur = -1, cnt = 0;
  float s = 0.f, mx = 0.f;
  for (int n = n0; n < n1; ++n) {
    int g = batch[n];  // wave-uniform, sorted
    float v = hbuf[(size_t)n * 64 + lane];
    float y = fmaxf(fmaf((v - m) * rs, ga, be), 0.f);
    if (g != cur) {
      if (cur >= 0) {
        atomicAdd(&gsum[cur * 64 + lane], s);
        atomicMax(&gmax[cur * 64 + lane], __float_as_uint(mx));
        if (lane == 0) atomicAdd(&gcnt[cur], cnt);
      }
      cur = g; s = 0.f; mx = 0.f; cnt = 0;
    }
    s += y; mx = fmaxf(mx, y); ++cnt;
  }
  if (cur >= 0) {
    atomicAdd(&gsum[cur * 64 + lane], s);
    atomicMax(&gmax[cur * 64 + lane], __float_as_uint(mx));
    if (lane == 0) atomicAdd(&gcnt[cur], cnt);
  }
}

// ---------- head layer 1 with fused pooling assembly ----------
__global__ void k_head_pool(const float* __restrict__ gsum,
                            const unsigned int* __restrict__ gmax,
                            const int* __restrict__ gcnt,
                            const float* __restrict__ W, const float* __restrict__ b,
                            const float* __restrict__ gamma, const float* __restrict__ beta,
                            float* __restrict__ out, int Kout) {
  int lane = threadIdx.x & 63;  // row (graph)
  int col = blockIdx.x * (blockDim.x >> 6) + (threadIdx.x >> 6);
  if (col >= Kout) return;
  float inv = 1.f / fmaxf((float)gcnt[lane], 1.f);
  float a = b[col];
#pragma unroll 4
  for (int k = 0; k < 64; ++k)
    a = fmaf(gsum[lane * 64 + k] * inv, W[(size_t)k * Kout + col], a);
#pragma unroll 4
  for (int k = 0; k < 64; ++k)
    a = fmaf(__uint_as_float(gmax[lane * 64 + k]), W[(size_t)(64 + k) * Kout + col], a);
  float sv = a, ss = a * a;
#pragma unroll
  for (int off = 32; off > 0; off >>= 1) {
    sv += __shfl_xor(sv, off);
    ss += __shfl_xor(ss, off);
  }
  float m = sv * (1.f / 64.f);
  float var = ss * (1.f / 64.f) - m * m;
  float y = fmaxf(fmaf((a - m) * rsqrtf(var + 1e-5f), gamma[col], beta[col]), 0.f);
  out[(size_t)lane * Kout + col] = y;
}

// ---------- head layer: out = relu(bn(in @ W + b)); wave = one column ----------
__global__ void k_head(const float* __restrict__ in, const float* __restrict__ W,
                       const float* __restrict__ b, const float* __restrict__ gamma,
                       const float* __restrict__ beta, float* __restrict__ out,
                       int Kin, int Kout) {
  int lane = threadIdx.x & 63;  // row (graph)
  int col = blockIdx.x * (blockDim.x >> 6) + (threadIdx.x >> 6);
  if (col >= Kout) return;
  const float4* ir = reinterpret_cast<const float4*>(in + (size_t)lane * Kin);
  float a = b[col];
  for (int k4 = 0; k4 < (Kin >> 2); ++k4) {
    float4 v = ir[k4];
    int k = k4 << 2;
    a = fmaf(v.x, W[(size_t)k * Kout + col], a);
    a = fmaf(v.y, W[(size_t)(k + 1) * Kout + col], a);
    a = fmaf(v.z, W[(size_t)(k + 2) * Kout + col], a);
    a = fmaf(v.w, W[(size_t)(k + 3) * Kout + col], a);
  }
  float sv = a, ss = a * a;
#pragma unroll
  for (int off = 32; off > 0; off >>= 1) {
    sv += __shfl_xor(sv, off);
    ss += __shfl_xor(ss, off);
  }
  float m = sv * (1.f / 64.f);
  float var = ss * (1.f / 64.f) - m * m;
  float y = fmaxf(fmaf((a - m) * rsqrtf(var + 1e-5f), gamma[col], beta[col]), 0.f);
  out[(size_t)lane * Kout + col] = y;
}

// ---------- final linear: [64,64] @ [64,10] + bout ----------
__global__ void k_out(const float* __restrict__ in, const float* __restrict__ W,
                      const float* __restrict__ b, float* __restrict__ out) {
  int t = threadIdx.x;
  if (t >= 640) return;
  int r = t / 10, c = t % 10;
  float a = b[c];
#pragma unroll
  for (int k = 0; k < 64; ++k) a = fmaf(in[r * 64 + k], W[k * 10 + c], a);
  out[t] = a;
}

extern "C" void kernel_launch(void* const* d_in, const int* in_sizes, int n_in,
                              void* d_out, int out_size, void* d_ws, size_t ws_size,
                              hipStream_t stream) {
  const float* x = (const float*)d_in[0];
  const int* ei = (const int*)d_in[1];
  const float* ea = (const float*)d_in[2];
  const int* batch = (const int*)d_in[3];
  const float* w_e1 = (const float*)d_in[4];
  const float* b_e1 = (const float*)d_in[5];
  const float* w_e2 = (const float*)d_in[6];
  const float* b_e2 = (const float*)d_in[7];
  const float* root = (const float*)d_in[8];
  const float* conv_bias = (const float*)d_in[9];
  const float* g_bnc = (const float*)d_in[10];
  const float* b_bnc = (const float*)d_in[11];
  const float* w1 = (const float*)d_in[12];
  const float* b1 = (const float*)d_in[13];
  const float* g1 = (const float*)d_in[14];
  const float* be1 = (const float*)d_in[15];
  const float* w2 = (const float*)d_in[16];
  const float* b2 = (const float*)d_in[17];
  const float* g2 = (const float*)d_in[18];
  const float* be2 = (const float*)d_in[19];
  const float* w3 = (const float*)d_in[20];
  const float* b3 = (const float*)d_in[21];
  const float* g3 = (const float*)d_in[22];
  const float* be3 = (const float*)d_in[23];
  const float* wout = (const float*)d_in[24];
  const float* bout = (const float*)d_in[25];

  int N = in_sizes[0] / 8;
  int E = in_sizes[1] / 2;

  char* wsb = (char*)d_ws;
  size_t off = 0;
  auto alloc = [&](size_t bytes) -> void* {
    void* p = wsb + off;
    off += (bytes + 255) & ~(size_t)255;
    return p;
  };
  float* he = (float*)alloc((size_t)E * 16 * 4);          // 32 MB
  int* cursor = (int*)alloc((size_t)N * 4);               // 0.2 MB
  int* slots = (int*)alloc((size_t)N * DEG_CAP * 4);      // 12.8 MB
  float* zbuf = (float*)alloc((size_t)N * ZROW * 4);      // 27.2 MB
  float* hbuf = (float*)alloc((size_t)N * 64 * 4);        // 12.8 MB
  float* zblk = (float*)alloc(8384 * 4);                  // stats+gsum+gmax+gcnt
  float* stats = zblk;                                    // 128
  float* gsum = zblk + 128;                               // 4096
  unsigned int* gmax = (unsigned int*)(zblk + 128 + 4096);// 4096
  int* gcnt = (int*)(zblk + 128 + 8192);                  // 64
  float* l1 = (float*)alloc(64 * 256 * 4);
  float* l2 = (float*)alloc(64 * 128 * 4);
  float* l3 = (float*)alloc(64 * 64 * 4);

  hipMemsetAsync(cursor, 0, (size_t)N * 4, stream);
  hipMemsetAsync(zblk, 0, 8384 * 4, stream);

  const int tb = 256;
  k_he<<<(E + tb - 1) / tb, tb, 0, stream>>>(ea, w_e1, b_e1, he, E);
  k_fill<<<(E + tb - 1) / tb, tb, 0, stream>>>(ei, cursor, slots, E);
  k_zgather<<<(N + 3) / 4, 256, 0, stream>>>(x, ei, he, cursor, slots, zbuf, N);
  k_wmix<<<768, 256, 0, stream>>>(x, cursor, zbuf, w_e2, b_e2, root, conv_bias,
                                  hbuf, stats, N);
  k_bnpool<<<512, 256, 0, stream>>>(hbuf, stats, batch, g_bnc, b_bnc, gsum, gmax, gcnt, N);
  k_head_pool<<<64, 256, 0, stream>>>(gsum, gmax, gcnt, w1, b1, g1, be1, l1, 256);
  k_head<<<32, 256, 0, stream>>>(l1, w2, b2, g2, be2, l2, 256, 128);
  k_head<<<16, 256, 0, stream>>>(l2, w3, b3, g3, be3, l3, 128, 64);
  k_out<<<1, 640, 0, stream>>>(l3, wout, bout, (float*)d_out);
}

// Round 7
// 308.655 us; speedup vs baseline: 8.5373x; 1.1936x over previous
//
#include <hip/hip_runtime.h>

#define DEG_CAP 64
#define ZROW 144   // 128 z + 8 xsum/deg + 8 x
#define ZPAD 148   // LDS row pad: (n*148)%32 spreads 8 banks -> 2-way (free)

__device__ __forceinline__ int rfl(int v) { return __builtin_amdgcn_readfirstlane(v); }

// ---------- edge MLP layer 1: he[E,16] = relu(ea @ w_e1 + b_e1) ----------
__global__ void k_he(const float* __restrict__ ea, const float* __restrict__ w,
                     const float* __restrict__ b, float* __restrict__ he, int E) {
  int e = blockIdx.x * blockDim.x + threadIdx.x;
  if (e >= E) return;
  const float4* eap = reinterpret_cast<const float4*>(ea + (size_t)e * 8);
  float4 a0 = eap[0], a1 = eap[1];
  float av[8] = {a0.x, a0.y, a0.z, a0.w, a1.x, a1.y, a1.z, a1.w};
  float o[16];
#pragma unroll
  for (int k = 0; k < 16; ++k) o[k] = b[k];
#pragma unroll
  for (int t = 0; t < 8; ++t) {
    float at = av[t];
#pragma unroll
    for (int k = 0; k < 16; ++k) o[k] = fmaf(at, w[t * 16 + k], o[k]);
  }
#pragma unroll
  for (int k = 0; k < 16; ++k) o[k] = fmaxf(o[k], 0.f);
  float4* hp = reinterpret_cast<float4*>(he + (size_t)e * 16);
  hp[0] = make_float4(o[0], o[1], o[2], o[3]);
  hp[1] = make_float4(o[4], o[5], o[6], o[7]);
  hp[2] = make_float4(o[8], o[9], o[10], o[11]);
  hp[3] = make_float4(o[12], o[13], o[14], o[15]);
}

// ---------- build capped CSR-by-dst ----------
__global__ void k_fill(const int* __restrict__ ei, int* __restrict__ cursor,
                       int* __restrict__ slots, int E) {
  int e = blockIdx.x * blockDim.x + threadIdx.x;
  if (e >= E) return;
  int dst = ei[E + e];
  int slot = atomicAdd(&cursor[dst], 1);
  if (slot < DEG_CAP) slots[(size_t)dst * DEG_CAP + slot] = e;
}

// ---------- phase A: z[n] = sum_e he[e] (x) x[src] (pre-scaled by 1/deg) ----------
// wave = node; lane l owns (k = l>>2, f = {2*(l&3), 2*(l&3)+1}): 2 FMA/edge.
// Row layout [ZROW]: [0..127] z/deg, [128..135] xsum/deg, [136..143] x[n].
__global__ void k_zgather(const float* __restrict__ x, const int* __restrict__ ei,
                          const float* __restrict__ he, const int* __restrict__ cursor,
                          const int* __restrict__ slots, float* __restrict__ zbuf,
                          int N) {
  int lane = threadIdx.x & 63;
  int n = rfl(blockIdx.x * (blockDim.x >> 6) + (threadIdx.x >> 6));
  if (n >= N) return;
  int k = lane >> 2;
  int f2 = (lane & 3) << 1;
  int d = cursor[n];                     // s_load (n uniform)
  int dc = min(d, DEG_CAP);
  int eid = (lane < dc) ? slots[(size_t)n * DEG_CAP + lane] : 0;
  int sid = ei[eid];  // per-lane gather, pre-loop (off critical path)
  float z0 = 0.f, z1 = 0.f, xs0 = 0.f, xs1 = 0.f;
  if (dc > 0) {
    int e0 = __shfl(eid, 0), s0 = __shfl(sid, 0);
    float hk = he[(size_t)e0 * 16 + k];
    float2 xv = *reinterpret_cast<const float2*>(x + (size_t)s0 * 8 + f2);
    for (int i = 1; i < dc; ++i) {   // 2-deep pipeline: next loads over current FMAs
      int e1 = __shfl(eid, i), s1 = __shfl(sid, i);
      float hk_n = he[(size_t)e1 * 16 + k];
      float2 xv_n = *reinterpret_cast<const float2*>(x + (size_t)s1 * 8 + f2);
      z0 = fmaf(hk, xv.x, z0);
      z1 = fmaf(hk, xv.y, z1);
      xs0 += xv.x; xs1 += xv.y;
      hk = hk_n; xv = xv_n;
    }
    z0 = fmaf(hk, xv.x, z0);
    z1 = fmaf(hk, xv.y, z1);
    xs0 += xv.x; xs1 += xv.y;
  }
  float inv = 1.f / (float)max(d, 1);
  z0 *= inv; z1 *= inv; xs0 *= inv; xs1 *= inv;
  float2* zp = reinterpret_cast<float2*>(zbuf + (size_t)n * ZROW);
  zp[lane] = make_float2(z0, z1);
  if (lane < 4) zp[64 + lane] = make_float2(xs0, xs1);
  if (lane < 8) zbuf[(size_t)n * ZROW + 136 + lane] = x[(size_t)n * 8 + lane];
}

// ---------- phase B: LDS-tiled GEMM hout[N,64] = Z[N,144] @ W[144,64] + cb ----------
// W rows: [0..127]=w_e2 (z-order), [128..135]=b_e2, [136..143]=root.
// Block: 64-node tile, 256 threads, 4x4 micro-tile per thread. BN stats fused.
__global__ __launch_bounds__(256) void k_zwgemm(
    const float* __restrict__ zbuf, const float* __restrict__ w_e2,
    const float* __restrict__ b_e2, const float* __restrict__ root,
    const float* __restrict__ conv_bias, float* __restrict__ hout,
    float* __restrict__ stats, int N) {
  __shared__ float wt[ZROW * 64];      // 36.9 KB, wt[j*64+h]
  __shared__ float zt[64 * ZPAD];      // 37.9 KB, zt[n*ZPAD+j]
  __shared__ float sl[128];
  int t = threadIdx.x;
  int n0 = blockIdx.x * 64;

  // stage W (coalesced in h)
  for (int i = t; i < ZROW * 64; i += 256) {
    int j = i >> 6, hh = i & 63;
    float v;
    if (j < 128) {
      int k = j >> 3, f = (((j >> 1) & 3) << 1) | (j & 1);
      v = w_e2[k * 512 + f * 64 + hh];
    } else if (j < 136) {
      v = b_e2[(j - 128) * 64 + hh];
    } else {
      v = root[(j - 136) * 64 + hh];
    }
    wt[i] = v;
  }
  // stage Z tile (float4 coalesced), zero-fill OOB rows
  for (int i4 = t; i4 < 64 * ZROW / 4; i4 += 256) {   // 9 iters
    int dw = i4 << 2;
    int r = dw / ZROW;
    int c = dw - r * ZROW;
    float4 v = make_float4(0.f, 0.f, 0.f, 0.f);
    if (n0 + r < N)
      v = *reinterpret_cast<const float4*>(zbuf + (size_t)(n0 + r) * ZROW + c);
    *reinterpret_cast<float4*>(&zt[r * ZPAD + c]) = v;
  }
  if (t < 128) sl[t] = 0.f;
  __syncthreads();

  int hg = t & 15;       // h-group: h = hg*4 + q
  int ng = t >> 4;       // node-group: n = n0 + ng*4 + i
  float acc[4][4];
#pragma unroll
  for (int i = 0; i < 4; ++i)
#pragma unroll
    for (int q = 0; q < 4; ++q) acc[i][q] = 0.f;

  for (int j = 0; j < ZROW; j += 4) {
    float za[4][4], wa[4][4];
#pragma unroll
    for (int i = 0; i < 4; ++i) {
      float4 v = *reinterpret_cast<const float4*>(&zt[(ng * 4 + i) * ZPAD + j]);
      za[i][0] = v.x; za[i][1] = v.y; za[i][2] = v.z; za[i][3] = v.w;
    }
#pragma unroll
    for (int r = 0; r < 4; ++r) {
      float4 v = *reinterpret_cast<const float4*>(&wt[(j + r) * 64 + hg * 4]);
      wa[r][0] = v.x; wa[r][1] = v.y; wa[r][2] = v.z; wa[r][3] = v.w;
    }
#pragma unroll
    for (int r = 0; r < 4; ++r)
#pragma unroll
      for (int i = 0; i < 4; ++i)
#pragma unroll
        for (int q = 0; q < 4; ++q)
          acc[i][q] = fmaf(za[i][r], wa[r][q], acc[i][q]);
  }

  // epilogue: + conv_bias, store, BN partial sums
  float cb[4];
#pragma unroll
  for (int q = 0; q < 4; ++q) cb[q] = conv_bias[hg * 4 + q];
  float bns[4] = {0.f, 0.f, 0.f, 0.f}, bnq[4] = {0.f, 0.f, 0.f, 0.f};
#pragma unroll
  for (int i = 0; i < 4; ++i) {
    int n = n0 + ng * 4 + i;
    float h0 = acc[i][0] + cb[0], h1 = acc[i][1] + cb[1];
    float h2 = acc[i][2] + cb[2], h3 = acc[i][3] + cb[3];
    if (n < N) {
      *reinterpret_cast<float4*>(&hout[(size_t)n * 64 + hg * 4]) =
          make_float4(h0, h1, h2, h3);
      bns[0] += h0; bns[1] += h1; bns[2] += h2; bns[3] += h3;
      bnq[0] += h0 * h0; bnq[1] += h1 * h1; bnq[2] += h2 * h2; bnq[3] += h3 * h3;
    }
  }
  // reduce over ng within wave (lane bits 4,5), then LDS, then global
#pragma unroll
  for (int q = 0; q < 4; ++q) {
    bns[q] += __shfl_xor(bns[q], 16); bns[q] += __shfl_xor(bns[q], 32);
    bnq[q] += __shfl_xor(bnq[q], 16); bnq[q] += __shfl_xor(bnq[q], 32);
  }
  if ((t & 48) == 0) {
#pragma unroll
    for (int q = 0; q < 4; ++q) {
      atomicAdd(&sl[hg * 4 + q], bns[q]);
      atomicAdd(&sl[64 + hg * 4 + q], bnq[q]);
    }
  }
  __syncthreads();
  if (t < 128) atomicAdd(&stats[t], sl[t]);
}

// ---------- BN+ReLU + per-graph pooling (batch_index sorted -> chunked) ----------
__global__ void k_bnpool(const float* __restrict__ hbuf, const float* __restrict__ stats,
                         const int* __restrict__ batch, const float* __restrict__ gamma,
                         const float* __restrict__ beta, float* __restrict__ gsum,
                         unsigned int* __restrict__ gmax, int* __restrict__ gcnt, int N) {
  int lane = threadIdx.x & 63;
  int wid = blockIdx.x * (blockDim.x >> 6) + (threadIdx.x >> 6);
  int nw = gridDim.x * (blockDim.x >> 6);
  float m = stats[lane] / (float)N;
  float var = stats[64 + lane] / (float)N - m * m;
  float rs = rsqrtf(var + 1e-5f);
  float ga = gamma[lane], be = beta[lane];
  int per = (N + nw - 1) / nw;
  int n0 = wid * per;
  int n1 = min(N, n0 + per);
  int cur = -1, cnt = 0;
  float s = 0.f, mx = 0.f;
  for (int n = n0; n < n1; ++n) {
    int g = batch[n];  // wave-uniform, sorted
    float v = hbuf[(size_t)n * 64 + lane];
    float y = fmaxf(fmaf((v - m) * rs, ga, be), 0.f);
    if (g != cur) {
      if (cur >= 0) {
        atomicAdd(&gsum[cur * 64 + lane], s);
        atomicMax(&gmax[cur * 64 + lane], __float_as_uint(mx));
        if (lane == 0) atomicAdd(&gcnt[cur], cnt);
      }
      cur = g; s = 0.f; mx = 0.f; cnt = 0;
    }
    s += y; mx = fmaxf(mx, y); ++cnt;
  }
  if (cur >= 0) {
    atomicAdd(&gsum[cur * 64 + lane], s);
    atomicMax(&gmax[cur * 64 + lane], __float_as_uint(mx));
    if (lane == 0) atomicAdd(&gcnt[cur], cnt);
  }
}

// ---------- head layer 1 with fused pooling assembly ----------
__global__ void k_head_pool(const float* __restrict__ gsum,
                            const unsigned int* __restrict__ gmax,
                            const int* __restrict__ gcnt,
                            const float* __restrict__ W, const float* __restrict__ b,
                            const float* __restrict__ gamma, const float* __restrict__ beta,
                            float* __restrict__ out, int Kout) {
  int lane = threadIdx.x & 63;  // row (graph)
  int col = blockIdx.x * (blockDim.x >> 6) + (threadIdx.x >> 6);
  if (col >= Kout) return;
  float inv = 1.f / fmaxf((float)gcnt[lane], 1.f);
  float a = b[col];
#pragma unroll 4
  for (int k = 0; k < 64; ++k)
    a = fmaf(gsum[lane * 64 + k] * inv, W[(size_t)k * Kout + col], a);
#pragma unroll 4
  for (int k = 0; k < 64; ++k)
    a = fmaf(__uint_as_float(gmax[lane * 64 + k]), W[(size_t)(64 + k) * Kout + col], a);
  float sv = a, ss = a * a;
#pragma unroll
  for (int off = 32; off > 0; off >>= 1) {
    sv += __shfl_xor(sv, off);
    ss += __shfl_xor(ss, off);
  }
  float m = sv * (1.f / 64.f);
  float var = ss * (1.f / 64.f) - m * m;
  float y = fmaxf(fmaf((a - m) * rsqrtf(var + 1e-5f), gamma[col], beta[col]), 0.f);
  out[(size_t)lane * Kout + col] = y;
}

// ---------- head layer: out = relu(bn(in @ W + b)); wave = one column ----------
__global__ void k_head(const float* __restrict__ in, const float* __restrict__ W,
                       const float* __restrict__ b, const float* __restrict__ gamma,
                       const float* __restrict__ beta, float* __restrict__ out,
                       int Kin, int Kout) {
  int lane = threadIdx.x & 63;  // row (graph)
  int col = blockIdx.x * (blockDim.x >> 6) + (threadIdx.x >> 6);
  if (col >= Kout) return;
  const float4* ir = reinterpret_cast<const float4*>(in + (size_t)lane * Kin);
  float a = b[col];
  for (int k4 = 0; k4 < (Kin >> 2); ++k4) {
    float4 v = ir[k4];
    int k = k4 << 2;
    a = fmaf(v.x, W[(size_t)k * Kout + col], a);
    a = fmaf(v.y, W[(size_t)(k + 1) * Kout + col], a);
    a = fmaf(v.z, W[(size_t)(k + 2) * Kout + col], a);
    a = fmaf(v.w, W[(size_t)(k + 3) * Kout + col], a);
  }
  float sv = a, ss = a * a;
#pragma unroll
  for (int off = 32; off > 0; off >>= 1) {
    sv += __shfl_xor(sv, off);
    ss += __shfl_xor(ss, off);
  }
  float m = sv * (1.f / 64.f);
  float var = ss * (1.f / 64.f) - m * m;
  float y = fmaxf(fmaf((a - m) * rsqrtf(var + 1e-5f), gamma[col], beta[col]), 0.f);
  out[(size_t)lane * Kout + col] = y;
}

// ---------- final linear: [64,64] @ [64,10] + bout ----------
__global__ void k_out(const float* __restrict__ in, const float* __restrict__ W,
                      const float* __restrict__ b, float* __restrict__ out) {
  int t = threadIdx.x;
  if (t >= 640) return;
  int r = t / 10, c = t % 10;
  float a = b[c];
#pragma unroll
  for (int k = 0; k < 64; ++k) a = fmaf(in[r * 64 + k], W[k * 10 + c], a);
  out[t] = a;
}

extern "C" void kernel_launch(void* const* d_in, const int* in_sizes, int n_in,
                              void* d_out, int out_size, void* d_ws, size_t ws_size,
                              hipStream_t stream) {
  const float* x = (const float*)d_in[0];
  const int* ei = (const int*)d_in[1];
  const float* ea = (const float*)d_in[2];
  const int* batch = (const int*)d_in[3];
  const float* w_e1 = (const float*)d_in[4];
  const float* b_e1 = (const float*)d_in[5];
  const float* w_e2 = (const float*)d_in[6];
  const float* b_e2 = (const float*)d_in[7];
  const float* root = (const float*)d_in[8];
  const float* conv_bias = (const float*)d_in[9];
  const float* g_bnc = (const float*)d_in[10];
  const float* b_bnc = (const float*)d_in[11];
  const float* w1 = (const float*)d_in[12];
  const float* b1 = (const float*)d_in[13];
  const float* g1 = (const float*)d_in[14];
  const float* be1 = (const float*)d_in[15];
  const float* w2 = (const float*)d_in[16];
  const float* b2 = (const float*)d_in[17];
  const float* g2 = (const float*)d_in[18];
  const float* be2 = (const float*)d_in[19];
  const float* w3 = (const float*)d_in[20];
  const float* b3 = (const float*)d_in[21];
  const float* g3 = (const float*)d_in[22];
  const float* be3 = (const float*)d_in[23];
  const float* wout = (const float*)d_in[24];
  const float* bout = (const float*)d_in[25];

  int N = in_sizes[0] / 8;
  int E = in_sizes[1] / 2;

  char* wsb = (char*)d_ws;
  size_t off = 0;
  auto alloc = [&](size_t bytes) -> void* {
    void* p = wsb + off;
    off += (bytes + 255) & ~(size_t)255;
    return p;
  };
  float* he = (float*)alloc((size_t)E * 16 * 4);          // 32 MB
  int* cursor = (int*)alloc((size_t)N * 4);               // 0.2 MB
  int* slots = (int*)alloc((size_t)N * DEG_CAP * 4);      // 12.8 MB
  float* zbuf = (float*)alloc((size_t)N * ZROW * 4);      // 28.8 MB
  float* hbuf = (float*)alloc((size_t)N * 64 * 4);        // 12.8 MB
  float* zblk = (float*)alloc(8384 * 4);                  // stats+gsum+gmax+gcnt
  float* stats = zblk;                                    // 128
  float* gsum = zblk + 128;                               // 4096
  unsigned int* gmax = (unsigned int*)(zblk + 128 + 4096);// 4096
  int* gcnt = (int*)(zblk + 128 + 8192);                  // 64
  float* l1 = (float*)alloc(64 * 256 * 4);
  float* l2 = (float*)alloc(64 * 128 * 4);
  float* l3 = (float*)alloc(64 * 64 * 4);

  hipMemsetAsync(cursor, 0, (size_t)N * 4, stream);
  hipMemsetAsync(zblk, 0, 8384 * 4, stream);

  const int tb = 256;
  k_he<<<(E + tb - 1) / tb, tb, 0, stream>>>(ea, w_e1, b_e1, he, E);
  k_fill<<<(E + tb - 1) / tb, tb, 0, stream>>>(ei, cursor, slots, E);
  k_zgather<<<(N + 3) / 4, 256, 0, stream>>>(x, ei, he, cursor, slots, zbuf, N);
  k_zwgemm<<<(N + 63) / 64, 256, 0, stream>>>(zbuf, w_e2, b_e2, root, conv_bias,
                                              hbuf, stats, N);
  k_bnpool<<<512, 256, 0, stream>>>(hbuf, stats, batch, g_bnc, b_bnc, gsum, gmax, gcnt, N);
  k_head_pool<<<64, 256, 0, stream>>>(gsum, gmax, gcnt, w1, b1, g1, be1, l1, 256);
  k_head<<<32, 256, 0, stream>>>(l1, w2, b2, g2, be2, l2, 256, 128);
  k_head<<<16, 256, 0, stream>>>(l2, w3, b3, g3, be3, l3, 128, 64);
  k_out<<<1, 640, 0, stream>>>(l3, wout, bout, (float*)d_out);
}